// Round 3
// baseline (182.137 us; speedup 1.0000x reference)
//
#include <hip/hip_runtime.h>

typedef float f32x2 __attribute__((ext_vector_type(2)));

#define D_IN 128
#define NH   16
#define APW  256   // atoms per wave-strip
#define BS   8     // atoms per load batch (double-buffered)

__device__ __forceinline__ void flush_seg(float r, int seg, float* __restrict__ out) {
    #pragma unroll
    for (int off = 32; off >= 1; off >>= 1) r += __shfl_xor(r, off, 64);
    if ((threadIdx.x & 63) == 0) atomicAdd(out + seg, r);
}

__global__ __launch_bounds__(256) void main_kernel(
        const float* __restrict__ x,
        const int*   __restrict__ sid,
        const float* __restrict__ W0,
        const float* __restrict__ W1,
        const float* __restrict__ W2,
        float*       __restrict__ out,
        int n, int nStrips, int totalWaves) {
    const int lane  = threadIdx.x & 63;
    const int waveG = (blockIdx.x << 2) + (threadIdx.x >> 6);

    // ---- per-wave redundant weight collapse: w = W0 @ (W1 @ W2).
    // Lane l holds w[2l], w[2l+1]. W1/W2 reads are wave-uniform (scalar
    // loads, L2-hot after the first blocks); W0 reads are 128 B/lane.
    f32x2 wv;
    {
        float v1[NH];
        #pragma unroll
        for (int t = 0; t < NH; ++t) {
            float s = 0.f;
            #pragma unroll
            for (int k = 0; k < NH; ++k) s += W1[t * NH + k] * W2[k];
            v1[t] = s;
        }
        float wx = 0.f, wy = 0.f;
        const float* r0 = W0 + (2 * lane) * NH;
        #pragma unroll
        for (int j = 0; j < NH; ++j) {
            wx += r0[j]      * v1[j];
            wy += r0[NH + j] * v1[j];
        }
        wv.x = wx; wv.y = wy;
    }

    const f32x2* __restrict__ x2 = reinterpret_cast<const f32x2*>(x);

    for (int strip = waveG; strip < nStrips; strip += totalWaves) {
        const int base  = strip * APW;
        const int count = min(APW, n - base);
        const f32x2* __restrict__ xs = x2 + (long long)base * 64 + lane;

        int   cur = sid[base];   // wave-uniform -> scalar load
        float r   = 0.f;

        if (count == APW) {
            f32x2 A[BS], B[BS];
            #pragma unroll
            for (int s = 0; s < BS; ++s) A[s] = __builtin_nontemporal_load(&xs[s * 64]);

            const int NB = APW / BS;   // 32, even
            for (int ib = 0; ib < NB; ib += 2) {
                {   // prefetch batch ib+1 -> B
                    const f32x2* p = xs + (ib + 1) * BS * 64;
                    #pragma unroll
                    for (int s = 0; s < BS; ++s) B[s] = __builtin_nontemporal_load(&p[s * 64]);
                }
                {   // process A
                    const int off = base + ib * BS;
                    int slast = sid[off + BS - 1];
                    if (slast == cur) {
                        #pragma unroll
                        for (int s = 0; s < BS; ++s) r += A[s].x * wv.x + A[s].y * wv.y;
                    } else {
                        #pragma unroll
                        for (int s = 0; s < BS; ++s) {
                            int cs = sid[off + s];
                            if (cs != cur) { flush_seg(r, cur, out); r = 0.f; cur = cs; }
                            r += A[s].x * wv.x + A[s].y * wv.y;
                        }
                    }
                }
                if (ib + 2 < NB) {   // prefetch batch ib+2 -> A
                    const f32x2* p = xs + (ib + 2) * BS * 64;
                    #pragma unroll
                    for (int s = 0; s < BS; ++s) A[s] = __builtin_nontemporal_load(&p[s * 64]);
                }
                {   // process B
                    const int off = base + (ib + 1) * BS;
                    int slast = sid[off + BS - 1];
                    if (slast == cur) {
                        #pragma unroll
                        for (int s = 0; s < BS; ++s) r += B[s].x * wv.x + B[s].y * wv.y;
                    } else {
                        #pragma unroll
                        for (int s = 0; s < BS; ++s) {
                            int cs = sid[off + s];
                            if (cs != cur) { flush_seg(r, cur, out); r = 0.f; cur = cs; }
                            r += B[s].x * wv.x + B[s].y * wv.y;
                        }
                    }
                }
            }
        } else {
            // tail strip (at most one wave hits this): simple guarded loop
            for (int s = 0; s < count; ++s) {
                int cs = sid[base + s];
                if (cs != cur) { flush_seg(r, cur, out); r = 0.f; cur = cs; }
                f32x2 xv = xs[s * 64];
                r += xv.x * wv.x + xv.y * wv.y;
            }
        }
        flush_seg(r, cur, out);
    }
}

extern "C" void kernel_launch(void* const* d_in, const int* in_sizes, int n_in,
                              void* d_out, int out_size, void* d_ws, size_t ws_size,
                              hipStream_t stream) {
    const float* x   = (const float*)d_in[0];
    const float* W0  = (const float*)d_in[1];
    const float* W1  = (const float*)d_in[2];
    const float* W2  = (const float*)d_in[3];
    const int*   sid = (const int*)d_in[4];
    float*       out = (float*)d_out;

    const int n = in_sizes[0] / D_IN;  // N_ATOMS

    // zero the accumulator (graph-capturable async memset; ~80 KB)
    hipMemsetAsync(out, 0, (size_t)out_size * sizeof(float), stream);

    // main: one 256-atom strip per wave
    const int nStrips = (n + APW - 1) / APW;
    int nblocks = (nStrips + 3) / 4;
    if (nblocks > 2048) nblocks = 2048;
    const int totalWaves = nblocks * 4;
    main_kernel<<<nblocks, 256, 0, stream>>>(x, sid, W0, W1, W2, out,
                                             n, nStrips, totalWaves);
}

// Round 4
// 176.321 us; speedup vs baseline: 1.0330x; 1.0330x over previous
//
#include <hip/hip_runtime.h>

typedef float f32x2 __attribute__((ext_vector_type(2)));

#define D_IN 128
#define NH   16
#define APW  256   // atoms per wave-strip
#define BS   8     // atoms per load batch (double-buffered)

// Prep: zero out[] and (block 0) collapse W0@W1@W2 -> w[128].
__global__ void prep_kernel(const float* __restrict__ W0,
                            const float* __restrict__ W1,
                            const float* __restrict__ W2,
                            float* __restrict__ w,
                            float* __restrict__ out, int m) {
    int i = blockIdx.x * blockDim.x + threadIdx.x;
    if (i < m) out[i] = 0.f;
    if (blockIdx.x == 0) {
        __shared__ float v1[NH];
        int t = threadIdx.x;
        if (t < NH) {
            float s = 0.f;
            #pragma unroll
            for (int k = 0; k < NH; ++k) s += W1[t * NH + k] * W2[k];
            v1[t] = s;
        }
        __syncthreads();
        if (t < D_IN) {
            float s = 0.f;
            #pragma unroll
            for (int j = 0; j < NH; ++j) s += W0[t * NH + j] * v1[j];
            w[t] = s;
        }
    }
}

__device__ __forceinline__ void flush_seg(float r, int seg, float* __restrict__ out) {
    #pragma unroll
    for (int off = 32; off >= 1; off >>= 1) r += __shfl_xor(r, off, 64);
    if ((threadIdx.x & 63) == 0) atomicAdd(out + seg, r);
}

__global__ __launch_bounds__(256) void main_kernel(
        const float* __restrict__ x,
        const int*   __restrict__ sid,
        const float* __restrict__ w,
        float*       __restrict__ out,
        int n, int nStrips, int totalWaves) {
    const int lane  = threadIdx.x & 63;
    const int waveG = __builtin_amdgcn_readfirstlane((blockIdx.x << 2) + (threadIdx.x >> 6));

    const f32x2* __restrict__ x2 = reinterpret_cast<const f32x2*>(x);
    const f32x2 wv = reinterpret_cast<const f32x2*>(w)[lane];

    for (int strip = waveG; strip < nStrips; strip += totalWaves) {
        const int base  = strip * APW;
        const int count = min(APW, n - base);
        const f32x2* __restrict__ xs = x2 + (long long)base * 64 + lane;

        int   cur = sid[base];   // scalar load (base is wave-uniform)
        float r   = 0.f;

        if (count == APW) {
            f32x2 A[BS], B[BS];
            #pragma unroll
            for (int s = 0; s < BS; ++s) A[s] = __builtin_nontemporal_load(&xs[s * 64]);

            const int NB = APW / BS;   // 32, even
            for (int ib = 0; ib < NB; ib += 2) {
                {   // prefetch batch ib+1 -> B
                    const f32x2* p = xs + (ib + 1) * BS * 64;
                    #pragma unroll
                    for (int s = 0; s < BS; ++s) B[s] = __builtin_nontemporal_load(&p[s * 64]);
                }
                {   // process A
                    const int off = base + ib * BS;
                    int slast = sid[off + BS - 1];
                    if (slast == cur) {
                        #pragma unroll
                        for (int s = 0; s < BS; ++s) r += A[s].x * wv.x + A[s].y * wv.y;
                    } else {
                        #pragma unroll
                        for (int s = 0; s < BS; ++s) {
                            int cs = sid[off + s];
                            if (cs != cur) { flush_seg(r, cur, out); r = 0.f; cur = cs; }
                            r += A[s].x * wv.x + A[s].y * wv.y;
                        }
                    }
                }
                if (ib + 2 < NB) {   // prefetch batch ib+2 -> A
                    const f32x2* p = xs + (ib + 2) * BS * 64;
                    #pragma unroll
                    for (int s = 0; s < BS; ++s) A[s] = __builtin_nontemporal_load(&p[s * 64]);
                }
                {   // process B
                    const int off = base + (ib + 1) * BS;
                    int slast = sid[off + BS - 1];
                    if (slast == cur) {
                        #pragma unroll
                        for (int s = 0; s < BS; ++s) r += B[s].x * wv.x + B[s].y * wv.y;
                    } else {
                        #pragma unroll
                        for (int s = 0; s < BS; ++s) {
                            int cs = sid[off + s];
                            if (cs != cur) { flush_seg(r, cur, out); r = 0.f; cur = cs; }
                            r += B[s].x * wv.x + B[s].y * wv.y;
                        }
                    }
                }
            }
        } else {
            // tail strip (at most one wave hits this): simple guarded loop
            for (int s = 0; s < count; ++s) {
                int cs = sid[base + s];
                if (cs != cur) { flush_seg(r, cur, out); r = 0.f; cur = cs; }
                f32x2 xv = xs[s * 64];
                r += xv.x * wv.x + xv.y * wv.y;
            }
        }
        flush_seg(r, cur, out);
    }
}

extern "C" void kernel_launch(void* const* d_in, const int* in_sizes, int n_in,
                              void* d_out, int out_size, void* d_ws, size_t ws_size,
                              hipStream_t stream) {
    const float* x   = (const float*)d_in[0];
    const float* W0  = (const float*)d_in[1];
    const float* W1  = (const float*)d_in[2];
    const float* W2  = (const float*)d_in[3];
    const int*   sid = (const int*)d_in[4];
    float*       out = (float*)d_out;
    float*       w   = (float*)d_ws;   // 128 floats of scratch

    const int n = in_sizes[0] / D_IN;  // N_ATOMS

    {   // prep: zero out[out_size] + compute w
        int blocks = (out_size + 255) / 256;
        if (blocks < 1) blocks = 1;
        prep_kernel<<<blocks, 256, 0, stream>>>(W0, W1, W2, w, out, out_size);
    }

    {   // main: one 256-atom strip per wave
        const int nStrips = (n + APW - 1) / APW;
        int nblocks = (nStrips + 3) / 4;
        if (nblocks > 2048) nblocks = 2048;
        const int totalWaves = nblocks * 4;
        main_kernel<<<nblocks, 256, 0, stream>>>(x, sid, w, out, n, nStrips, totalWaves);
    }
}